// Round 11
// baseline (804.357 us; speedup 1.0000x reference)
//
#include <hip/hip_runtime.h>
#include <hip/hip_bf16.h>
#include <math.h>
#include <cstddef>
#include <stdint.h>

#define NN 20000
#define EE 320000
#define RR 8
#define PP 100000
#define NR (NN * RR)   // 160000 = 625*256

typedef __hip_bfloat16 bf16;
typedef __attribute__((ext_vector_type(8))) short short8;
typedef __attribute__((ext_vector_type(4))) short short4v;
typedef __attribute__((ext_vector_type(4))) float floatx4;

__device__ __forceinline__ float b2f(bf16 v) { return __bfloat162float(v); }
__device__ __forceinline__ bf16 f2b(float v) { return __float2bfloat16(v); }
__device__ __forceinline__ float bits2f(unsigned short u) {
  unsigned int i = ((unsigned int)u) << 16; float f; __builtin_memcpy(&f, &i, 4); return f;
}
__device__ __forceinline__ short f2bits(float f) {
  bf16 h = __float2bfloat16(f); short s; __builtin_memcpy(&s, &h, 2); return s;
}
__device__ __forceinline__ float gelu_f(float y) {
  return 0.5f * y * (1.f + erff(y * 0.7071067811865476f));
}
// async global->LDS, 16B per lane; lds base wave-uniform, lane i lands at base+i*16
__device__ __forceinline__ void async_copy16(void* lds, const void* g) {
  __builtin_amdgcn_global_load_lds((const __attribute__((address_space(1))) void*)g,
                                   (__attribute__((address_space(3))) void*)lds, 16, 0, 0);
}
// swizzled fragment address, [rows][64] bf16 tile (stride 64): chunk q lives at q^(row&7)
__device__ __forceinline__ const short8* frag_at(const bf16* base, int row, int q) {
  return (const short8*)(base + row * 64 + (((q) ^ (row & 7)) << 3));
}
// stride-256 variant (col64 = 64-col group base), and stride-128 variant (qg = global chunk)
__device__ __forceinline__ const short8* frag256(const bf16* base, int row, int col64, int q) {
  return (const short8*)(base + row * 256 + col64 + (((q) ^ (row & 7)) << 3));
}
__device__ __forceinline__ int idx128(int row, int qg) {
  return row * 128 + ((qg >> 3) << 6) + (((qg & 7) ^ (row & 7)) << 3);
}

// ---------------- CSR build ----------------
__global__ void hist_k(const int* __restrict__ dst, const int* __restrict__ et,
                       int* __restrict__ counts) {
  int e = blockIdx.x * 256 + threadIdx.x;
  if (e >= EE) return;
  atomicAdd(&counts[dst[e] * RR + et[e]], 1);
}

__global__ void scan1_k(const int* __restrict__ counts, int* __restrict__ prefix,
                        int* __restrict__ bsums) {
  __shared__ int tmp[256];
  int i = blockIdx.x * 256 + threadIdx.x;
  int v = counts[i];
  tmp[threadIdx.x] = v; __syncthreads();
  for (int off = 1; off < 256; off <<= 1) {
    int x = (threadIdx.x >= off) ? tmp[threadIdx.x - off] : 0;
    __syncthreads();
    tmp[threadIdx.x] += x;
    __syncthreads();
  }
  prefix[i] = tmp[threadIdx.x] - v;
  if (threadIdx.x == 255) bsums[blockIdx.x] = tmp[255];
}

__global__ void scan2_k(int* __restrict__ bsums, int nb) {
  __shared__ int tmp[256];
  __shared__ int carry;
  if (threadIdx.x == 0) carry = 0;
  __syncthreads();
  for (int base = 0; base < nb; base += 256) {
    int i = base + threadIdx.x;
    int v = (i < nb) ? bsums[i] : 0;
    tmp[threadIdx.x] = v; __syncthreads();
    for (int off = 1; off < 256; off <<= 1) {
      int x = (threadIdx.x >= off) ? tmp[threadIdx.x - off] : 0;
      __syncthreads();
      tmp[threadIdx.x] += x;
      __syncthreads();
    }
    int c = carry;
    if (i < nb) bsums[i] = c + tmp[threadIdx.x] - v;
    __syncthreads();
    if (threadIdx.x == 255) carry = c + tmp[255];
    __syncthreads();
  }
}

__global__ void scan3_k(int* __restrict__ prefix, const int* __restrict__ bsums) {
  int i = blockIdx.x * 256 + threadIdx.x;
  prefix[i] += bsums[blockIdx.x];
}

__global__ void scatter_k(const int* __restrict__ src, const int* __restrict__ dst,
                          const int* __restrict__ et, const int* __restrict__ segstart,
                          int* __restrict__ cursor, int* __restrict__ ssrc) {
  int e = blockIdx.x * 256 + threadIdx.x;
  if (e >= EE) return;
  int s = dst[e] * RR + et[e];
  int pos = atomicAdd(&cursor[s], 1);
  ssrc[segstart[s] + pos] = src[e];
}

// ---------------- small prep kernels ----------------
__global__ void cvt_bf16_k(const float* __restrict__ in, bf16* __restrict__ out, int n) {
  int i = blockIdx.x * 256 + threadIdx.x;
  if (i < n) out[i] = f2b(in[i]);
}

__global__ void softmax4_k(const float* r0, const float* r1, const float* r2,
                           const float* r3, float* __restrict__ a) {
  if (threadIdx.x == 0) {
    const float* rs[4] = {r0, r1, r2, r3};
    for (int l = 0; l < 4; ++l) {
      float mx = -1e30f;
      for (int i = 0; i < RR; ++i) mx = fmaxf(mx, rs[l][i]);
      float e[RR]; float s = 0.f;
      for (int i = 0; i < RR; ++i) { e[i] = expf(rs[l][i] - mx); s += e[i]; }
      for (int i = 0; i < RR; ++i) a[l * RR + i] = e[i] / s;
    }
  }
}

__global__ void transpose_k(const float* __restrict__ in, bf16* __restrict__ out,
                            int rows, int cols) {
  int idx = blockIdx.x * 256 + threadIdx.x;
  if (idx >= rows * cols) return;
  int r = idx / cols, c = idx - r * cols;
  out[(size_t)c * rows + r] = f2b(in[idx]);
}

// coalesced: consecutive threads -> consecutive o -> basis reads coalesced
__global__ void prep_w_k(const float* __restrict__ basis, const float* __restrict__ att,
                         const float* __restrict__ root, const float* __restrict__ a,
                         bf16* __restrict__ Wt, int ic, int icsh, int oc, int ocsh) {
  int idx = blockIdx.x * 256 + threadIdx.x;
  int cols = 9 * ic;
  if (idx >= cols * oc) return;
  int o = idx & (oc - 1);
  int col = idx >> ocsh;
  int r = col >> icsh;
  int k = col & (ic - 1);
  float val;
  if (r < RR) {
    float acc = 0.f;
    for (int bb = 0; bb < RR; ++bb)
      acc += att[r * RR + bb] * basis[((size_t)bb * ic + k) * oc + o];
    val = a[r] * acc;
  } else {
    val = root[(size_t)k * oc + o];
  }
  Wt[(size_t)o * cols + col] = f2b(val);
}

// ---------------- aggregation (segment sums + self row) ----------------
__global__ __launch_bounds__(256) void aggregate_k(
    const bf16* __restrict__ h, const int* __restrict__ segstart,
    const int* __restrict__ counts, const int* __restrict__ ssrc,
    bf16* __restrict__ agg, int ic, int tpnsh) {
  int tpn = 1 << tpnsh;
  int npb = 256 >> tpnsh;
  int local = threadIdx.x >> tpnsh;
  int n = blockIdx.x * npb + local;
  if (n >= NN) return;
  int cbase = (threadIdx.x & (tpn - 1)) * 8;
  size_t rowoff = (size_t)n * (9 * ic);
  for (int r = 0; r < RR; ++r) {
    int s = n * RR + r;
    int st = segstart[s];
    int cnt = counts[s];
    float a[8] = {0.f, 0.f, 0.f, 0.f, 0.f, 0.f, 0.f, 0.f};
    for (int i = 0; i < cnt; ++i) {
      int src = ssrc[st + i];
      short8 v = *(const short8*)(h + (size_t)src * ic + cbase);
#pragma unroll
      for (int j = 0; j < 8; ++j) a[j] += bits2f((unsigned short)v[j]);
    }
    short8 o;
#pragma unroll
    for (int j = 0; j < 8; ++j) o[j] = f2bits(a[j]);
    *(short8*)(agg + rowoff + r * ic + cbase) = o;
  }
  *(short8*)(agg + rowoff + 8 * ic + cbase) =
      *(const short8*)(h + (size_t)n * ic + cbase);
}

// ---------------- split-N bf16 GEMM, fp32 out (conv layers): 128x64 tiles ----------------
// 1D grid, XCD-pinned swizzle: bid%8 = XCD. All nb N-members of a 128-row A
// group run on one XCD -> A fetched from HBM once into that XCD's L2.
__global__ __launch_bounds__(256) void gemm_f32_k(
    const bf16* __restrict__ A, const bf16* __restrict__ Wt,
    float* __restrict__ Cf, int M, int N, int K, int nb) {
  const int bid = blockIdx.x;
  const int xcd = bid & 7;
  const int slot = bid >> 3;
  const int gidx = slot / nb;
  const int member = slot - gidx * nb;
  const int mb = (M + 127) >> 7;
  const int m = gidx * 8 + xcd;
  if (m >= mb) return;
  const int m0 = m * 128;
  const int n0 = member * 64;

  __shared__ __align__(16) bf16 As[128 * 64];
  __shared__ __align__(16) bf16 Ws[64 * 64];
  const int tid = threadIdx.x;
  const int wave = tid >> 6, lane = tid & 63;
  const int quad = lane >> 4, l16 = lane & 15;
  const int wm = (wave >> 1) * 64, wn = (wave & 1) * 32;
  floatx4 acc[4][2];
#pragma unroll
  for (int i = 0; i < 4; ++i)
#pragma unroll
    for (int j = 0; j < 2; ++j) acc[i][j] = (floatx4){0.f, 0.f, 0.f, 0.f};

  for (int k0 = 0; k0 < K; k0 += 64) {
#pragma unroll
    for (int q = 0; q < 4; ++q) {
      int c0 = (wave * 4 + q) * 1024;
      int row = (c0 >> 7) + (lane >> 3);
      int grow = m0 + row; if (grow >= M) grow = M - 1;
      int ch = (lane & 7) ^ (row & 7);
      async_copy16((char*)As + c0, A + (size_t)grow * K + k0 + ch * 8);
    }
#pragma unroll
    for (int q = 0; q < 2; ++q) {
      int c0 = (wave * 2 + q) * 1024;
      int row = (c0 >> 7) + (lane >> 3);
      int ch = (lane & 7) ^ (row & 7);
      async_copy16((char*)Ws + c0, Wt + (size_t)(n0 + row) * K + k0 + ch * 8);
    }
    __syncthreads();
#pragma unroll
    for (int kk = 0; kk < 64; kk += 32) {
      int qb = (kk >> 3) + quad;
      short8 b0 = *frag_at(Ws, wn + l16, qb);
      short8 b1 = *frag_at(Ws, wn + 16 + l16, qb);
#pragma unroll
      for (int i = 0; i < 4; ++i) {
        short8 a = *frag_at(As, wm + i * 16 + l16, qb);
        acc[i][0] = __builtin_amdgcn_mfma_f32_16x16x32_bf16(a, b0, acc[i][0], 0, 0, 0);
        acc[i][1] = __builtin_amdgcn_mfma_f32_16x16x32_bf16(a, b1, acc[i][1], 0, 0, 0);
      }
    }
    __syncthreads();
  }
#pragma unroll
  for (int i = 0; i < 4; ++i)
#pragma unroll
    for (int j = 0; j < 2; ++j)
#pragma unroll
      for (int r = 0; r < 4; ++r) {
        int row = m0 + wm + i * 16 + quad * 4 + r;
        int col = n0 + wn + j * 16 + l16;
        if (row < M) Cf[(size_t)row * N + col] = acc[i][j][r];
      }
}

// ---------------- plain bf16 GEMM (residuals, ZA): bf16 out, 64x64; grid (N/64, M/64) ----------------
__global__ __launch_bounds__(256) void gemm_plain_k(
    const bf16* __restrict__ A, const bf16* __restrict__ Wt,
    bf16* __restrict__ Cb, int M, int N, int K) {
  __shared__ __align__(16) bf16 As[64 * 64];
  __shared__ __align__(16) bf16 Ws[64 * 64];
  const int m0 = blockIdx.y * 64;
  const int n0 = blockIdx.x * 64;
  const int tid = threadIdx.x;
  const int wave = tid >> 6, lane = tid & 63;
  const int quad = lane >> 4, l16 = lane & 15;
  const int wm = (wave >> 1) * 32, wn = (wave & 1) * 32;
  floatx4 acc00 = {0.f, 0.f, 0.f, 0.f};
  floatx4 acc01 = acc00, acc10 = acc00, acc11 = acc00;

  for (int k0 = 0; k0 < K; k0 += 64) {
#pragma unroll
    for (int q = 0; q < 2; ++q) {
      int c0 = (wave * 2 + q) * 1024;
      int row = (c0 >> 7) + (lane >> 3);
      int grow = m0 + row; if (grow >= M) grow = M - 1;
      int ch = (lane & 7) ^ (row & 7);
      async_copy16((char*)As + c0, A + (size_t)grow * K + k0 + ch * 8);
    }
#pragma unroll
    for (int q = 0; q < 2; ++q) {
      int c0 = (wave * 2 + q) * 1024;
      int row = (c0 >> 7) + (lane >> 3);
      int ch = (lane & 7) ^ (row & 7);
      async_copy16((char*)Ws + c0, Wt + (size_t)(n0 + row) * K + k0 + ch * 8);
    }
    __syncthreads();
#pragma unroll
    for (int kk = 0; kk < 64; kk += 32) {
      int qb = (kk >> 3) + quad;
      short8 a0 = *frag_at(As, wm + l16, qb);
      short8 a1 = *frag_at(As, wm + 16 + l16, qb);
      short8 b0 = *frag_at(Ws, wn + l16, qb);
      short8 b1 = *frag_at(Ws, wn + 16 + l16, qb);
      acc00 = __builtin_amdgcn_mfma_f32_16x16x32_bf16(a0, b0, acc00, 0, 0, 0);
      acc01 = __builtin_amdgcn_mfma_f32_16x16x32_bf16(a0, b1, acc01, 0, 0, 0);
      acc10 = __builtin_amdgcn_mfma_f32_16x16x32_bf16(a1, b0, acc10, 0, 0, 0);
      acc11 = __builtin_amdgcn_mfma_f32_16x16x32_bf16(a1, b1, acc11, 0, 0, 0);
    }
    __syncthreads();
  }
  floatx4 accs[2][2] = {{acc00, acc01}, {acc10, acc11}};
#pragma unroll
  for (int i = 0; i < 2; ++i)
#pragma unroll
    for (int j = 0; j < 2; ++j)
#pragma unroll
      for (int r = 0; r < 4; ++r) {
        int row = m0 + wm + i * 16 + quad * 4 + r;
        int col = n0 + wn + j * 16 + l16;
        if (row < M) Cb[(size_t)row * N + col] = f2b(accs[i][j][r]);
      }
}

// ---------------- LN (+residual, +gelu) for conv layers ----------------
__global__ __launch_bounds__(256) void ln_conv_k(
    const float* __restrict__ conv, const bf16* __restrict__ res,
    const float* __restrict__ g, const float* __restrict__ b,
    bf16* __restrict__ out, float* __restrict__ zout, int oc, int do_gelu) {
  int wave = threadIdx.x >> 6, lane = threadIdx.x & 63;
  int row = blockIdx.x * 4 + wave;
  if (row >= NN) return;
  int ne = oc >> 6;
  float v[4];
  float s = 0.f, s2 = 0.f;
  for (int i = 0; i < ne; ++i) {
    v[i] = conv[(size_t)row * oc + i * 64 + lane];
    s += v[i]; s2 += v[i] * v[i];
  }
  for (int off = 32; off; off >>= 1) { s += __shfl_xor(s, off); s2 += __shfl_xor(s2, off); }
  float m = s / oc;
  float var = s2 / oc - m * m;
  float rs = rsqrtf(var + 1e-5f);
  for (int i = 0; i < ne; ++i) {
    int c = i * 64 + lane;
    float y = (v[i] - m) * rs * g[c] + b[c];
    y += b2f(res[(size_t)row * oc + c]);
    if (zout) zout[(size_t)row * oc + c] = y;
    if (do_gelu) y = gelu_f(y);
    out[(size_t)row * oc + c] = f2b(y);
  }
}

// ---------------- decoder GEMM0 (split-N, pre-LN bf16 out, XCD-pinned) ----------------
// P0[p][n] = (zi*zj)@WB + |zi-zj|@WC  (K=256; linear (zi+zj)@WA hoisted to ZA,
// added in lngemm1's staging). tile 128 pairs x 64 cols; XCD-swizzled (nb=4).
__global__ __launch_bounds__(256) void gemm_pe_k(
    const bf16* __restrict__ z, const int* __restrict__ pairs,
    const bf16* __restrict__ WBT, const bf16* __restrict__ WCT,  // each [256][128]
    bf16* __restrict__ P0) {
  const int bid = blockIdx.x;
  const int xcd = bid & 7;
  const int slot = bid >> 3;
  const int gidx = slot >> 2;          // nb = 4
  const int member = slot & 3;
  const int mb = (PP + 127) >> 7;
  const int m = gidx * 8 + xcd;
  if (m >= mb) return;
  const int m0 = m * 128;
  const int n0 = member * 64;

  __shared__ __align__(16) bf16 PEs[128 * 64];
  __shared__ __align__(16) bf16 Ws[64 * 64];
  const int tid = threadIdx.x;
  const int wave = tid >> 6, lane = tid & 63;
  const int quad = lane >> 4, l16 = lane & 15;
  const int wm = (wave >> 1) * 64, wn = (wave & 1) * 32;

  const int prow = tid >> 1;          // 0..127
  const int colq = (tid & 1) * 32;
  int pp = m0 + prow; if (pp >= PP) pp = PP - 1;
  const bf16* zi = z + (size_t)pairs[pp] * 128;
  const bf16* zj = z + (size_t)pairs[PP + pp] * 128;

  floatx4 acc[4][2];
#pragma unroll
  for (int i = 0; i < 4; ++i)
#pragma unroll
    for (int j = 0; j < 2; ++j) acc[i][j] = (floatx4){0.f, 0.f, 0.f, 0.f};

#pragma unroll
  for (int kwi = 0; kwi < 2; ++kwi) {
    const int kw = kwi * 64;
    short8 va[4], vb[4];
#pragma unroll
    for (int c8 = 0; c8 < 4; ++c8) {
      va[c8] = *(const short8*)(zi + kw + colq + c8 * 8);
      vb[c8] = *(const short8*)(zj + kw + colq + c8 * 8);
    }
#pragma unroll
    for (int op = 0; op < 2; ++op) {   // 0: prod (WB), 1: absdiff (WC)
      const bf16* W = (op == 0) ? WBT : WCT;
#pragma unroll
      for (int q = 0; q < 2; ++q) {
        int c0 = q * 4096 + wave * 1024;
        int row = (c0 >> 7) + (lane >> 3);
        int ch = (lane & 7) ^ (row & 7);
        async_copy16((char*)Ws + c0, W + (size_t)(n0 + row) * 128 + kw + ch * 8);
      }
#pragma unroll
      for (int c8 = 0; c8 < 4; ++c8) {
        short8 o;
#pragma unroll
        for (int jj = 0; jj < 8; ++jj) {
          float fa = bits2f((unsigned short)va[c8][jj]);
          float fb = bits2f((unsigned short)vb[c8][jj]);
          float v = (op == 0) ? (fa * fb) : fabsf(fa - fb);
          o[jj] = f2bits(v);
        }
        int q = (tid & 1) * 4 + c8;
        *(short8*)(PEs + prow * 64 + ((q ^ (prow & 7)) << 3)) = o;
      }
      __syncthreads();
#pragma unroll
      for (int kk = 0; kk < 64; kk += 32) {
        int qb = (kk >> 3) + quad;
        short8 b0 = *frag_at(Ws, wn + l16, qb);
        short8 b1 = *frag_at(Ws, wn + 16 + l16, qb);
#pragma unroll
        for (int i = 0; i < 4; ++i) {
          short8 a = *frag_at(PEs, wm + i * 16 + l16, qb);
          acc[i][0] = __builtin_amdgcn_mfma_f32_16x16x32_bf16(a, b0, acc[i][0], 0, 0, 0);
          acc[i][1] = __builtin_amdgcn_mfma_f32_16x16x32_bf16(a, b1, acc[i][1], 0, 0, 0);
        }
      }
      __syncthreads();
    }
  }

#pragma unroll
  for (int i = 0; i < 4; ++i)
#pragma unroll
    for (int j = 0; j < 2; ++j)
#pragma unroll
      for (int r = 0; r < 4; ++r) {
        int row = m0 + wm + i * 16 + quad * 4 + r;
        int col = n0 + wn + j * 16 + l16;
        if (row < PP) P0[(size_t)row * 256 + col] = f2b(acc[i][j][r]);
      }
}

// ---------------- decoder GEMM1 with fused LN: ----------------
// A = gelu(ln(P0 + ZA[gi] + ZA[gj] + db0)) staged in LDS; P1 = A@W1^T + db1
__global__ __launch_bounds__(256) void lngemm1_k(
    const bf16* __restrict__ P0, const int* __restrict__ pairs,
    const bf16* __restrict__ ZA, const float* __restrict__ db0,
    const float* __restrict__ g0, const float* __restrict__ b0,
    const bf16* __restrict__ W1t,  // [128][256]
    const float* __restrict__ bias, bf16* __restrict__ P1, int M) {
  __shared__ __align__(16) bf16 As[64 * 256];
  __shared__ __align__(16) bf16 Ws[128 * 64];
  const int tid = threadIdx.x;
  const int wave = tid >> 6, lane = tid & 63;
  const int quad = lane >> 4, l16 = lane & 15;
  const int wr = (wave >> 1) * 32;
  const int wc = (wave & 1) * 64;
  const int m0 = blockIdx.x * 64;

  // stage A with fused bias+ZA+LN+GELU (4 threads per row, 64 cols each)
  {
    const int srow = tid >> 2;
    const int q4 = tid & 3;
    int grow = m0 + srow; if (grow >= M) grow = M - 1;
    int gi = pairs[grow], gj = pairs[PP + grow];
    const bf16* src = P0 + (size_t)grow * 256 + q4 * 64;
    const bf16* zai = ZA + (size_t)gi * 256 + q4 * 64;
    const bf16* zaj = ZA + (size_t)gj * 256 + q4 * 64;
    float v[64];
    float s = 0.f, s2 = 0.f;
#pragma unroll
    for (int c8 = 0; c8 < 8; ++c8) {
      short8 xp = *(const short8*)(src + c8 * 8);
      short8 xa = *(const short8*)(zai + c8 * 8);
      short8 xb = *(const short8*)(zaj + c8 * 8);
#pragma unroll
      for (int jj = 0; jj < 8; ++jj) {
        float f = bits2f((unsigned short)xp[jj]) + bits2f((unsigned short)xa[jj]) +
                  bits2f((unsigned short)xb[jj]) + db0[q4 * 64 + c8 * 8 + jj];
        v[c8 * 8 + jj] = f; s += f; s2 += f * f;
      }
    }
    s += __shfl_xor(s, 1); s2 += __shfl_xor(s2, 1);
    s += __shfl_xor(s, 2); s2 += __shfl_xor(s2, 2);
    float mean = s / 256.f;
    float var = s2 / 256.f - mean * mean;
    float rs = rsqrtf(var + 1e-5f);
#pragma unroll
    for (int c8 = 0; c8 < 8; ++c8) {
      short8 o;
#pragma unroll
      for (int jj = 0; jj < 8; ++jj) {
        int col = q4 * 64 + c8 * 8 + jj;
        float y = (v[c8 * 8 + jj] - mean) * rs * g0[col] + b0[col];
        o[jj] = f2bits(gelu_f(y));
      }
      *(short8*)(As + srow * 256 + q4 * 64 + ((c8 ^ (srow & 7)) << 3)) = o;
    }
  }

  floatx4 acc[2][4];
#pragma unroll
  for (int i = 0; i < 2; ++i)
#pragma unroll
    for (int j = 0; j < 4; ++j) acc[i][j] = (floatx4){0.f, 0.f, 0.f, 0.f};

  for (int kc = 0; kc < 4; ++kc) {
#pragma unroll
    for (int q = 0; q < 4; ++q) {
      int c0 = q * 4096 + wave * 1024;
      int row = (c0 >> 7) + (lane >> 3);
      int ch = (lane & 7) ^ (row & 7);
      async_copy16((char*)Ws + c0, W1t + (size_t)row * 256 + kc * 64 + ch * 8);
    }
    __syncthreads();
#pragma unroll
    for (int kk = 0; kk < 64; kk += 32) {
      int qb = (kk >> 3) + quad;
      short8 a0 = *frag256(As, wr + l16, kc * 64, qb);
      short8 a1 = *frag256(As, wr + 16 + l16, kc * 64, qb);
#pragma unroll
      for (int j = 0; j < 4; ++j) {
        short8 bb = *frag_at(Ws, wc + j * 16 + l16, qb);
        acc[0][j] = __builtin_amdgcn_mfma_f32_16x16x32_bf16(a0, bb, acc[0][j], 0, 0, 0);
        acc[1][j] = __builtin_amdgcn_mfma_f32_16x16x32_bf16(a1, bb, acc[1][j], 0, 0, 0);
      }
    }
    __syncthreads();
  }

#pragma unroll
  for (int i = 0; i < 2; ++i)
#pragma unroll
    for (int r = 0; r < 4; ++r) {
      int row = wr + i * 16 + quad * 4 + r;
      int grow = m0 + row;
      if (grow >= M) continue;
#pragma unroll
      for (int j = 0; j < 4; ++j) {
        int col = wc + j * 16 + l16;
        P1[(size_t)grow * 128 + col] = f2b(acc[i][j][r] + bias[col]);
      }
    }
}

// ---------------- decoder GEMM2: A = gelu(ln(P1)); P2 = A@W2^T + db2 ----------------
__global__ __launch_bounds__(256) void lngemm2_k(
    const bf16* __restrict__ P1, const bf16* __restrict__ W2t,  // [64][128]
    const float* __restrict__ g, const float* __restrict__ b,
    const float* __restrict__ bias, bf16* __restrict__ P2, int M) {
  __shared__ __align__(16) bf16 As[64 * 128];
  __shared__ __align__(16) bf16 Ws[64 * 64];
  const int tid = threadIdx.x;
  const int wave = tid >> 6, lane = tid & 63;
  const int quad = lane >> 4, l16 = lane & 15;
  const int m0 = blockIdx.x * 64;

  {
    const int srow = tid >> 2;
    const int q4 = tid & 3;
    int grow = m0 + srow; if (grow >= M) grow = M - 1;
    const bf16* src = P1 + (size_t)grow * 128 + q4 * 32;
    float v[32];
    float s = 0.f, s2 = 0.f;
#pragma unroll
    for (int c8 = 0; c8 < 4; ++c8) {
      short8 x = *(const short8*)(src + c8 * 8);
#pragma unroll
      for (int jj = 0; jj < 8; ++jj) {
        float f = bits2f((unsigned short)x[jj]);
        v[c8 * 8 + jj] = f; s += f; s2 += f * f;
      }
    }
    s += __shfl_xor(s, 1); s2 += __shfl_xor(s2, 1);
    s += __shfl_xor(s, 2); s2 += __shfl_xor(s2, 2);
    float mean = s / 128.f;
    float var = s2 / 128.f - mean * mean;
    float rs = rsqrtf(var + 1e-5f);
#pragma unroll
    for (int c8 = 0; c8 < 4; ++c8) {
      short8 o;
#pragma unroll
      for (int jj = 0; jj < 8; ++jj) {
        int col = q4 * 32 + c8 * 8 + jj;
        float y = (v[c8 * 8 + jj] - mean) * rs * g[col] + b[col];
        o[jj] = f2bits(gelu_f(y));
      }
      *(short8*)(As + idx128(srow, q4 * 4 + c8)) = o;
    }
  }

  floatx4 acc[4];
#pragma unroll
  for (int j = 0; j < 4; ++j) acc[j] = (floatx4){0.f, 0.f, 0.f, 0.f};

  for (int kc = 0; kc < 2; ++kc) {
#pragma unroll
    for (int q = 0; q < 2; ++q) {
      int c0 = q * 4096 + wave * 1024;
      int row = (c0 >> 7) + (lane >> 3);
      int ch = (lane & 7) ^ (row & 7);
      async_copy16((char*)Ws + c0, W2t + (size_t)row * 128 + kc * 64 + ch * 8);
    }
    __syncthreads();
#pragma unroll
    for (int kk = 0; kk < 64; kk += 32) {
      int qb = (kk >> 3) + quad;
      short8 a = *(const short8*)(As + idx128(wave * 16 + l16, kc * 8 + qb));
#pragma unroll
      for (int j = 0; j < 4; ++j) {
        short8 bb = *frag_at(Ws, j * 16 + l16, qb);
        acc[j] = __builtin_amdgcn_mfma_f32_16x16x32_bf16(a, bb, acc[j], 0, 0, 0);
      }
    }
    __syncthreads();
  }

#pragma unroll
  for (int r = 0; r < 4; ++r) {
    int row = wave * 16 + quad * 4 + r;
    int grow = m0 + row;
    if (grow >= M) continue;
#pragma unroll
    for (int j = 0; j < 4; ++j) {
      int col = j * 16 + l16;
      P2[(size_t)grow * 64 + col] = f2b(acc[j][r] + bias[col]);
    }
  }
}

// ---------------- logits: ln + gelu + dot ----------------
__global__ __launch_bounds__(256) void logits_k(const bf16* __restrict__ P2,
                                                const float* __restrict__ g,
                                                const float* __restrict__ b,
                                                const float* __restrict__ w3,
                                                const float* __restrict__ b3,
                                                float* __restrict__ out) {
  int wave = threadIdx.x >> 6, lane = threadIdx.x & 63;
  int p = blockIdx.x * 4 + wave;
  if (p >= PP) return;
  float v = b2f(P2[(size_t)p * 64 + lane]);
  float s = v, s2 = v * v;
  for (int off = 32; off; off >>= 1) { s += __shfl_xor(s, off); s2 += __shfl_xor(s2, off); }
  float m = s / 64.f;
  float var = s2 / 64.f - m * m;
  float rs = rsqrtf(var + 1e-5f);
  float y = gelu_f((v - m) * rs * g[lane] + b[lane]);
  float t = y * w3[lane];
  for (int off = 32; off; off >>= 1) t += __shfl_xor(t, off);
  if (lane == 0) out[p] = t + b3[0];
}

// ---------------- host ----------------
extern "C" void kernel_launch(void* const* d_in, const int* in_sizes, int n_in,
                              void* d_out, int out_size, void* d_ws, size_t ws_size,
                              hipStream_t stream) {
  auto cdiv = [](int a, int b) { return (a + b - 1) / b; };

  const float* x = (const float*)d_in[0];
  const int* ei = (const int*)d_in[1];
  const int* et = (const int*)d_in[2];
  const int* gp = (const int*)d_in[3];
  const float *basis[4], *att[4], *root[4], *relatt[4], *gln[4], *bln[4];
  for (int l = 0; l < 4; ++l) {
    basis[l]  = (const float*)d_in[4 + 6 * l];
    att[l]    = (const float*)d_in[5 + 6 * l];
    root[l]   = (const float*)d_in[6 + 6 * l];
    relatt[l] = (const float*)d_in[7 + 6 * l];
    gln[l]    = (const float*)d_in[8 + 6 * l];
    bln[l]    = (const float*)d_in[9 + 6 * l];
  }
  const float* res0 = (const float*)d_in[28];
  const float* res3 = (const float*)d_in[29];
  const float* dW0 = (const float*)d_in[30]; const float* db0 = (const float*)d_in[31];
  const float* dg0 = (const float*)d_in[32]; const float* dbb0 = (const float*)d_in[33];
  const float* dW1 = (const float*)d_in[34]; const float* db1 = (const float*)d_in[35];
  const float* dg1 = (const float*)d_in[36]; const float* dbb1 = (const float*)d_in[37];
  const float* dW2 = (const float*)d_in[38]; const float* db2 = (const float*)d_in[39];
  const float* dg2 = (const float*)d_in[40]; const float* dbb2 = (const float*)d_in[41];
  const float* dW3 = (const float*)d_in[42]; const float* db3 = (const float*)d_in[43];

  char* base = (char*)d_ws;
  size_t off = 0;
  auto alloc = [&](size_t bytes) -> char* {
    char* p = base + off;
    off += (bytes + 255) & ~(size_t)255;
    return p;
  };
  bf16* X16 = (bf16*)alloc((size_t)NN * 128 * 2);
  bf16* HA  = (bf16*)alloc((size_t)NN * 256 * 2);
  bf16* HB  = (bf16*)alloc((size_t)NN * 256 * 2);
  bf16* RESB = (bf16*)alloc((size_t)NN * 256 * 2);
  bf16* ZA   = (bf16*)alloc((size_t)NN * 256 * 2);
  float* CONV = (float*)alloc((size_t)NN * 256 * 4);
  bf16* WT    = (bf16*)alloc((size_t)589824 * 2);
  bf16* RES0T = (bf16*)alloc((size_t)32768 * 2);
  bf16* RES3T = (bf16*)alloc((size_t)32768 * 2);
  bf16* WAT   = (bf16*)alloc((size_t)32768 * 2);
  bf16* WBT   = (bf16*)alloc((size_t)32768 * 2);
  bf16* WCT   = (bf16*)alloc((size_t)32768 * 2);
  bf16* DW1T  = (bf16*)alloc((size_t)32768 * 2);
  bf16* DW2T  = (bf16*)alloc((size_t)8192 * 2);
  float* ASOFT = (float*)alloc(32 * 4);
  int* COUNTS = (int*)alloc((size_t)NR * 4);
  int* SEG    = (int*)alloc((size_t)NR * 4);
  int* CUR    = (int*)alloc((size_t)NR * 4);
  int* BS     = (int*)alloc(1024 * 4);
  int* SSRC   = (int*)alloc((size_t)EE * 4);
  char* BIG = alloc(93000000);   // overlay: AGG [N,2304]bf16 (92.2MB) | P0 [P,256]bf16 (51.2MB)
  bf16* AGG = (bf16*)BIG;
  bf16* P0  = (bf16*)BIG;
  bf16* P1  = (bf16*)alloc((size_t)PP * 128 * 2);
  bf16* P2  = (bf16*)alloc((size_t)PP * 64 * 2);
  (void)ws_size; (void)in_sizes; (void)n_in; (void)out_size;

  float* out_logits = (float*)d_out;
  float* out_z = (float*)d_out + PP;

  // --- CSR build ---
  hipMemsetAsync(COUNTS, 0, (size_t)NR * 4, stream);
  hipMemsetAsync(CUR, 0, (size_t)NR * 4, stream);
  hist_k<<<cdiv(EE, 256), 256, 0, stream>>>(ei + EE, et, COUNTS);
  scan1_k<<<NR / 256, 256, 0, stream>>>(COUNTS, SEG, BS);
  scan2_k<<<1, 256, 0, stream>>>(BS, NR / 256);
  scan3_k<<<NR / 256, 256, 0, stream>>>(SEG, BS);
  scatter_k<<<cdiv(EE, 256), 256, 0, stream>>>(ei, ei + EE, et, SEG, CUR, SSRC);

  // --- weight prep ---
  cvt_bf16_k<<<cdiv(NN * 128, 256), 256, 0, stream>>>(x, X16, NN * 128);
  softmax4_k<<<1, 64, 0, stream>>>(relatt[0], relatt[1], relatt[2], relatt[3], ASOFT);
  transpose_k<<<cdiv(128 * 256, 256), 256, 0, stream>>>(res0, RES0T, 128, 256);
  transpose_k<<<cdiv(256 * 128, 256), 256, 0, stream>>>(res3, RES3T, 256, 128);
  transpose_k<<<cdiv(128 * 256, 256), 256, 0, stream>>>(dW0, WAT, 128, 256);
  transpose_k<<<cdiv(128 * 256, 256), 256, 0, stream>>>(dW0 + 128 * 256, WBT, 128, 256);
  transpose_k<<<cdiv(128 * 256, 256), 256, 0, stream>>>(dW0 + 256 * 256, WCT, 128, 256);
  transpose_k<<<cdiv(256 * 128, 256), 256, 0, stream>>>(dW1, DW1T, 256, 128);
  transpose_k<<<cdiv(128 * 64, 256), 256, 0, stream>>>(dW2, DW2T, 128, 64);

  const int mb = cdiv(NN, 128);            // 157
  const int swzP4 = 8 * cdiv(mb, 8) * 4;   // nb=4
  const int swzP2 = 8 * cdiv(mb, 8) * 2;   // nb=2

  // --- layer 0: ic=128, oc=256, residual = x @ res0 ---
  prep_w_k<<<cdiv(9 * 128 * 256, 256), 256, 0, stream>>>(basis[0], att[0], root[0], ASOFT + 0, WT, 128, 7, 256, 8);
  aggregate_k<<<cdiv(NN, 16), 256, 0, stream>>>(X16, SEG, COUNTS, SSRC, AGG, 128, 4);
  gemm_plain_k<<<dim3(4, cdiv(NN, 64)), 256, 0, stream>>>(X16, RES0T, RESB, NN, 256, 128);
  gemm_f32_k<<<swzP4, 256, 0, stream>>>(AGG, WT, CONV, NN, 256, 1152, 4);
  ln_conv_k<<<cdiv(NN, 4), 256, 0, stream>>>(CONV, RESB, gln[0], bln[0], HA, nullptr, 256, 1);

  // --- layer 1 ---
  prep_w_k<<<cdiv(9 * 256 * 256, 256), 256, 0, stream>>>(basis[1], att[1], root[1], ASOFT + 8, WT, 256, 8, 256, 8);
  aggregate_k<<<cdiv(NN, 8), 256, 0, stream>>>(HA, SEG, COUNTS, SSRC, AGG, 256, 5);
  gemm_f32_k<<<swzP4, 256, 0, stream>>>(AGG, WT, CONV, NN, 256, 2304, 4);
  ln_conv_k<<<cdiv(NN, 4), 256, 0, stream>>>(CONV, HA, gln[1], bln[1], HB, nullptr, 256, 1);

  // --- layer 2 ---
  prep_w_k<<<cdiv(9 * 256 * 256, 256), 256, 0, stream>>>(basis[2], att[2], root[2], ASOFT + 16, WT, 256, 8, 256, 8);
  aggregate_k<<<cdiv(NN, 8), 256, 0, stream>>>(HB, SEG, COUNTS, SSRC, AGG, 256, 5);
  gemm_f32_k<<<swzP4, 256, 0, stream>>>(AGG, WT, CONV, NN, 256, 2304, 4);
  ln_conv_k<<<cdiv(NN, 4), 256, 0, stream>>>(CONV, HB, gln[2], bln[2], HA, nullptr, 256, 1);

  // --- layer 3: oc=128, residual = h_in @ res3, no gelu; writes z (fp32 out_z) + HB ---
  prep_w_k<<<cdiv(9 * 256 * 128, 256), 256, 0, stream>>>(basis[3], att[3], root[3], ASOFT + 24, WT, 256, 8, 128, 7);
  aggregate_k<<<cdiv(NN, 8), 256, 0, stream>>>(HA, SEG, COUNTS, SSRC, AGG, 256, 5);
  gemm_plain_k<<<dim3(2, cdiv(NN, 64)), 256, 0, stream>>>(HA, RES3T, RESB, NN, 128, 256);
  gemm_f32_k<<<swzP2, 256, 0, stream>>>(AGG, WT, CONV, NN, 128, 2304, 2);
  ln_conv_k<<<cdiv(NN, 4), 256, 0, stream>>>(CONV, RESB, gln[3], bln[3], HB, out_z, 128, 0);

  // --- decoder ---
  gemm_plain_k<<<dim3(4, cdiv(NN, 64)), 256, 0, stream>>>(HB, WAT, ZA, NN, 256, 128);
  const int pb = cdiv(PP, 128);            // 782
  const int swzPE = 8 * cdiv(pb, 8) * 4;   // nb=4
  gemm_pe_k<<<swzPE, 256, 0, stream>>>(HB, gp, WBT, WCT, P0);
  lngemm1_k<<<cdiv(PP, 64), 256, 0, stream>>>(P0, gp, ZA, db0, dg0, dbb0, DW1T, db1, P1, PP);
  lngemm2_k<<<cdiv(PP, 64), 256, 0, stream>>>(P1, DW2T, dg1, dbb1, db2, P2, PP);
  logits_k<<<cdiv(PP, 4), 256, 0, stream>>>(P2, dg2, dbb2, dW3, db3, out_logits);
}

// Round 12
// 748.998 us; speedup vs baseline: 1.0739x; 1.0739x over previous
//
#include <hip/hip_runtime.h>
#include <hip/hip_bf16.h>
#include <math.h>
#include <cstddef>
#include <stdint.h>

#define NN 20000
#define EE 320000
#define RR 8
#define PP 100000
#define NR (NN * RR)   // 160000 = 625*256

typedef __hip_bfloat16 bf16;
typedef __attribute__((ext_vector_type(8))) short short8;
typedef __attribute__((ext_vector_type(4))) short short4v;
typedef __attribute__((ext_vector_type(4))) float floatx4;

__device__ __forceinline__ float b2f(bf16 v) { return __bfloat162float(v); }
__device__ __forceinline__ bf16 f2b(float v) { return __float2bfloat16(v); }
__device__ __forceinline__ float bits2f(unsigned short u) {
  unsigned int i = ((unsigned int)u) << 16; float f; __builtin_memcpy(&f, &i, 4); return f;
}
__device__ __forceinline__ short f2bits(float f) {
  bf16 h = __float2bfloat16(f); short s; __builtin_memcpy(&s, &h, 2); return s;
}
// fast tanh-form gelu: x*sigmoid(2t), t = 0.79788456*(x + 0.044715*x^3).
// 0.5*(1+tanh(t)) == 1/(1+e^{-2t}) == rcp(1 + 2^{-2.885390082*t}).
// max |delta| vs exact-erf gelu ~3e-4 << bf16 quantization noise.
__device__ __forceinline__ float gelu_f(float x) {
  float t = x * (0.7978845608f + 0.0356774081f * x * x);
  float s = exp2f(-2.885390082f * t);
  return x * __builtin_amdgcn_rcpf(1.f + s);
}
// async global->LDS, 16B per lane; lds base wave-uniform, lane i lands at base+i*16
__device__ __forceinline__ void async_copy16(void* lds, const void* g) {
  __builtin_amdgcn_global_load_lds((const __attribute__((address_space(1))) void*)g,
                                   (__attribute__((address_space(3))) void*)lds, 16, 0, 0);
}
// swizzled fragment address, [rows][64] bf16 tile (stride 64): chunk q lives at q^(row&7)
__device__ __forceinline__ const short8* frag_at(const bf16* base, int row, int q) {
  return (const short8*)(base + row * 64 + (((q) ^ (row & 7)) << 3));
}
// stride-256 variant (col64 = 64-col group base), and stride-128 variant (qg = global chunk)
__device__ __forceinline__ const short8* frag256(const bf16* base, int row, int col64, int q) {
  return (const short8*)(base + row * 256 + col64 + (((q) ^ (row & 7)) << 3));
}
__device__ __forceinline__ int idx128(int row, int qg) {
  return row * 128 + ((qg >> 3) << 6) + (((qg & 7) ^ (row & 7)) << 3);
}

// ---------------- CSR build ----------------
__global__ void hist_k(const int* __restrict__ dst, const int* __restrict__ et,
                       int* __restrict__ counts) {
  int e = blockIdx.x * 256 + threadIdx.x;
  if (e >= EE) return;
  atomicAdd(&counts[dst[e] * RR + et[e]], 1);
}

__global__ void scan1_k(const int* __restrict__ counts, int* __restrict__ prefix,
                        int* __restrict__ bsums) {
  __shared__ int tmp[256];
  int i = blockIdx.x * 256 + threadIdx.x;
  int v = counts[i];
  tmp[threadIdx.x] = v; __syncthreads();
  for (int off = 1; off < 256; off <<= 1) {
    int x = (threadIdx.x >= off) ? tmp[threadIdx.x - off] : 0;
    __syncthreads();
    tmp[threadIdx.x] += x;
    __syncthreads();
  }
  prefix[i] = tmp[threadIdx.x] - v;
  if (threadIdx.x == 255) bsums[blockIdx.x] = tmp[255];
}

__global__ void scan2_k(int* __restrict__ bsums, int nb) {
  __shared__ int tmp[256];
  __shared__ int carry;
  if (threadIdx.x == 0) carry = 0;
  __syncthreads();
  for (int base = 0; base < nb; base += 256) {
    int i = base + threadIdx.x;
    int v = (i < nb) ? bsums[i] : 0;
    tmp[threadIdx.x] = v; __syncthreads();
    for (int off = 1; off < 256; off <<= 1) {
      int x = (threadIdx.x >= off) ? tmp[threadIdx.x - off] : 0;
      __syncthreads();
      tmp[threadIdx.x] += x;
      __syncthreads();
    }
    int c = carry;
    if (i < nb) bsums[i] = c + tmp[threadIdx.x] - v;
    __syncthreads();
    if (threadIdx.x == 255) carry = c + tmp[255];
    __syncthreads();
  }
}

__global__ void scan3_k(int* __restrict__ prefix, const int* __restrict__ bsums) {
  int i = blockIdx.x * 256 + threadIdx.x;
  prefix[i] += bsums[blockIdx.x];
}

__global__ void scatter_k(const int* __restrict__ src, const int* __restrict__ dst,
                          const int* __restrict__ et, const int* __restrict__ segstart,
                          int* __restrict__ cursor, int* __restrict__ ssrc) {
  int e = blockIdx.x * 256 + threadIdx.x;
  if (e >= EE) return;
  int s = dst[e] * RR + et[e];
  int pos = atomicAdd(&cursor[s], 1);
  ssrc[segstart[s] + pos] = src[e];
}

// ---------------- small prep kernels ----------------
__global__ void cvt_bf16_k(const float* __restrict__ in, bf16* __restrict__ out, int n) {
  int i = blockIdx.x * 256 + threadIdx.x;
  if (i < n) out[i] = f2b(in[i]);
}

__global__ void softmax4_k(const float* r0, const float* r1, const float* r2,
                           const float* r3, float* __restrict__ a) {
  if (threadIdx.x == 0) {
    const float* rs[4] = {r0, r1, r2, r3};
    for (int l = 0; l < 4; ++l) {
      float mx = -1e30f;
      for (int i = 0; i < RR; ++i) mx = fmaxf(mx, rs[l][i]);
      float e[RR]; float s = 0.f;
      for (int i = 0; i < RR; ++i) { e[i] = expf(rs[l][i] - mx); s += e[i]; }
      for (int i = 0; i < RR; ++i) a[l * RR + i] = e[i] / s;
    }
  }
}

__global__ void transpose_k(const float* __restrict__ in, bf16* __restrict__ out,
                            int rows, int cols) {
  int idx = blockIdx.x * 256 + threadIdx.x;
  if (idx >= rows * cols) return;
  int r = idx / cols, c = idx - r * cols;
  out[(size_t)c * rows + r] = f2b(in[idx]);
}

// coalesced: consecutive threads -> consecutive o -> basis reads coalesced
__global__ void prep_w_k(const float* __restrict__ basis, const float* __restrict__ att,
                         const float* __restrict__ root, const float* __restrict__ a,
                         bf16* __restrict__ Wt, int ic, int icsh, int oc, int ocsh) {
  int idx = blockIdx.x * 256 + threadIdx.x;
  int cols = 9 * ic;
  if (idx >= cols * oc) return;
  int o = idx & (oc - 1);
  int col = idx >> ocsh;
  int r = col >> icsh;
  int k = col & (ic - 1);
  float val;
  if (r < RR) {
    float acc = 0.f;
    for (int bb = 0; bb < RR; ++bb)
      acc += att[r * RR + bb] * basis[((size_t)bb * ic + k) * oc + o];
    val = a[r] * acc;
  } else {
    val = root[(size_t)k * oc + o];
  }
  Wt[(size_t)o * cols + col] = f2b(val);
}

// ---------------- aggregation (segment sums + self row) ----------------
__global__ __launch_bounds__(256) void aggregate_k(
    const bf16* __restrict__ h, const int* __restrict__ segstart,
    const int* __restrict__ counts, const int* __restrict__ ssrc,
    bf16* __restrict__ agg, int ic, int tpnsh) {
  int tpn = 1 << tpnsh;
  int npb = 256 >> tpnsh;
  int local = threadIdx.x >> tpnsh;
  int n = blockIdx.x * npb + local;
  if (n >= NN) return;
  int cbase = (threadIdx.x & (tpn - 1)) * 8;
  size_t rowoff = (size_t)n * (9 * ic);
  for (int r = 0; r < RR; ++r) {
    int s = n * RR + r;
    int st = segstart[s];
    int cnt = counts[s];
    float a[8] = {0.f, 0.f, 0.f, 0.f, 0.f, 0.f, 0.f, 0.f};
    for (int i = 0; i < cnt; ++i) {
      int src = ssrc[st + i];
      short8 v = *(const short8*)(h + (size_t)src * ic + cbase);
#pragma unroll
      for (int j = 0; j < 8; ++j) a[j] += bits2f((unsigned short)v[j]);
    }
    short8 o;
#pragma unroll
    for (int j = 0; j < 8; ++j) o[j] = f2bits(a[j]);
    *(short8*)(agg + rowoff + r * ic + cbase) = o;
  }
  *(short8*)(agg + rowoff + 8 * ic + cbase) =
      *(const short8*)(h + (size_t)n * ic + cbase);
}

// ---------------- split-N bf16 GEMM, fp32 out (conv layers): 128x64 tiles ----------------
// 1D grid, XCD-pinned swizzle: bid%8 = XCD. All nb N-members of a 128-row A
// group run on one XCD -> A fetched from HBM once into that XCD's L2.
__global__ __launch_bounds__(256) void gemm_f32_k(
    const bf16* __restrict__ A, const bf16* __restrict__ Wt,
    float* __restrict__ Cf, int M, int N, int K, int nb) {
  const int bid = blockIdx.x;
  const int xcd = bid & 7;
  const int slot = bid >> 3;
  const int gidx = slot / nb;
  const int member = slot - gidx * nb;
  const int mb = (M + 127) >> 7;
  const int m = gidx * 8 + xcd;
  if (m >= mb) return;
  const int m0 = m * 128;
  const int n0 = member * 64;

  __shared__ __align__(16) bf16 As[128 * 64];
  __shared__ __align__(16) bf16 Ws[64 * 64];
  const int tid = threadIdx.x;
  const int wave = tid >> 6, lane = tid & 63;
  const int quad = lane >> 4, l16 = lane & 15;
  const int wm = (wave >> 1) * 64, wn = (wave & 1) * 32;
  floatx4 acc[4][2];
#pragma unroll
  for (int i = 0; i < 4; ++i)
#pragma unroll
    for (int j = 0; j < 2; ++j) acc[i][j] = (floatx4){0.f, 0.f, 0.f, 0.f};

  for (int k0 = 0; k0 < K; k0 += 64) {
#pragma unroll
    for (int q = 0; q < 4; ++q) {
      int c0 = (wave * 4 + q) * 1024;
      int row = (c0 >> 7) + (lane >> 3);
      int grow = m0 + row; if (grow >= M) grow = M - 1;
      int ch = (lane & 7) ^ (row & 7);
      async_copy16((char*)As + c0, A + (size_t)grow * K + k0 + ch * 8);
    }
#pragma unroll
    for (int q = 0; q < 2; ++q) {
      int c0 = (wave * 2 + q) * 1024;
      int row = (c0 >> 7) + (lane >> 3);
      int ch = (lane & 7) ^ (row & 7);
      async_copy16((char*)Ws + c0, Wt + (size_t)(n0 + row) * K + k0 + ch * 8);
    }
    __syncthreads();
#pragma unroll
    for (int kk = 0; kk < 64; kk += 32) {
      int qb = (kk >> 3) + quad;
      short8 b0 = *frag_at(Ws, wn + l16, qb);
      short8 b1 = *frag_at(Ws, wn + 16 + l16, qb);
#pragma unroll
      for (int i = 0; i < 4; ++i) {
        short8 a = *frag_at(As, wm + i * 16 + l16, qb);
        acc[i][0] = __builtin_amdgcn_mfma_f32_16x16x32_bf16(a, b0, acc[i][0], 0, 0, 0);
        acc[i][1] = __builtin_amdgcn_mfma_f32_16x16x32_bf16(a, b1, acc[i][1], 0, 0, 0);
      }
    }
    __syncthreads();
  }
#pragma unroll
  for (int i = 0; i < 4; ++i)
#pragma unroll
    for (int j = 0; j < 2; ++j)
#pragma unroll
      for (int r = 0; r < 4; ++r) {
        int row = m0 + wm + i * 16 + quad * 4 + r;
        int col = n0 + wn + j * 16 + l16;
        if (row < M) Cf[(size_t)row * N + col] = acc[i][j][r];
      }
}

// ---------------- plain bf16 GEMM (residuals, ZA): bf16 out, 64x64; grid (N/64, M/64) ----------------
__global__ __launch_bounds__(256) void gemm_plain_k(
    const bf16* __restrict__ A, const bf16* __restrict__ Wt,
    bf16* __restrict__ Cb, int M, int N, int K) {
  __shared__ __align__(16) bf16 As[64 * 64];
  __shared__ __align__(16) bf16 Ws[64 * 64];
  const int m0 = blockIdx.y * 64;
  const int n0 = blockIdx.x * 64;
  const int tid = threadIdx.x;
  const int wave = tid >> 6, lane = tid & 63;
  const int quad = lane >> 4, l16 = lane & 15;
  const int wm = (wave >> 1) * 32, wn = (wave & 1) * 32;
  floatx4 acc00 = {0.f, 0.f, 0.f, 0.f};
  floatx4 acc01 = acc00, acc10 = acc00, acc11 = acc00;

  for (int k0 = 0; k0 < K; k0 += 64) {
#pragma unroll
    for (int q = 0; q < 2; ++q) {
      int c0 = (wave * 2 + q) * 1024;
      int row = (c0 >> 7) + (lane >> 3);
      int grow = m0 + row; if (grow >= M) grow = M - 1;
      int ch = (lane & 7) ^ (row & 7);
      async_copy16((char*)As + c0, A + (size_t)grow * K + k0 + ch * 8);
    }
#pragma unroll
    for (int q = 0; q < 2; ++q) {
      int c0 = (wave * 2 + q) * 1024;
      int row = (c0 >> 7) + (lane >> 3);
      int ch = (lane & 7) ^ (row & 7);
      async_copy16((char*)Ws + c0, Wt + (size_t)(n0 + row) * K + k0 + ch * 8);
    }
    __syncthreads();
#pragma unroll
    for (int kk = 0; kk < 64; kk += 32) {
      int qb = (kk >> 3) + quad;
      short8 a0 = *frag_at(As, wm + l16, qb);
      short8 a1 = *frag_at(As, wm + 16 + l16, qb);
      short8 b0 = *frag_at(Ws, wn + l16, qb);
      short8 b1 = *frag_at(Ws, wn + 16 + l16, qb);
      acc00 = __builtin_amdgcn_mfma_f32_16x16x32_bf16(a0, b0, acc00, 0, 0, 0);
      acc01 = __builtin_amdgcn_mfma_f32_16x16x32_bf16(a0, b1, acc01, 0, 0, 0);
      acc10 = __builtin_amdgcn_mfma_f32_16x16x32_bf16(a1, b0, acc10, 0, 0, 0);
      acc11 = __builtin_amdgcn_mfma_f32_16x16x32_bf16(a1, b1, acc11, 0, 0, 0);
    }
    __syncthreads();
  }
  floatx4 accs[2][2] = {{acc00, acc01}, {acc10, acc11}};
#pragma unroll
  for (int i = 0; i < 2; ++i)
#pragma unroll
    for (int j = 0; j < 2; ++j)
#pragma unroll
      for (int r = 0; r < 4; ++r) {
        int row = m0 + wm + i * 16 + quad * 4 + r;
        int col = n0 + wn + j * 16 + l16;
        if (row < M) Cb[(size_t)row * N + col] = f2b(accs[i][j][r]);
      }
}

// ---------------- LN (+residual, +gelu) for conv layers ----------------
__global__ __launch_bounds__(256) void ln_conv_k(
    const float* __restrict__ conv, const bf16* __restrict__ res,
    const float* __restrict__ g, const float* __restrict__ b,
    bf16* __restrict__ out, float* __restrict__ zout, int oc, int do_gelu) {
  int wave = threadIdx.x >> 6, lane = threadIdx.x & 63;
  int row = blockIdx.x * 4 + wave;
  if (row >= NN) return;
  int ne = oc >> 6;
  float v[4];
  float s = 0.f, s2 = 0.f;
  for (int i = 0; i < ne; ++i) {
    v[i] = conv[(size_t)row * oc + i * 64 + lane];
    s += v[i]; s2 += v[i] * v[i];
  }
  for (int off = 32; off; off >>= 1) { s += __shfl_xor(s, off); s2 += __shfl_xor(s2, off); }
  float m = s / oc;
  float var = s2 / oc - m * m;
  float rs = rsqrtf(var + 1e-5f);
  for (int i = 0; i < ne; ++i) {
    int c = i * 64 + lane;
    float y = (v[i] - m) * rs * g[c] + b[c];
    y += b2f(res[(size_t)row * oc + c]);
    if (zout) zout[(size_t)row * oc + c] = y;
    if (do_gelu) y = gelu_f(y);
    out[(size_t)row * oc + c] = f2b(y);
  }
}

// ---------------- decoder GEMM0 (split-N, pre-LN bf16 out, XCD-pinned) ----------------
// P0[p][n] = (zi*zj)@WB + |zi-zj|@WC  (K=256; linear (zi+zj)@WA hoisted to ZA,
// added in ln_d0_k). tile 128 pairs x 64 cols; XCD-swizzled (nb=4).
__global__ __launch_bounds__(256) void gemm_pe_k(
    const bf16* __restrict__ z, const int* __restrict__ pairs,
    const bf16* __restrict__ WBT, const bf16* __restrict__ WCT,  // each [256][128]
    bf16* __restrict__ P0) {
  const int bid = blockIdx.x;
  const int xcd = bid & 7;
  const int slot = bid >> 3;
  const int gidx = slot >> 2;          // nb = 4
  const int member = slot & 3;
  const int mb = (PP + 127) >> 7;
  const int m = gidx * 8 + xcd;
  if (m >= mb) return;
  const int m0 = m * 128;
  const int n0 = member * 64;

  __shared__ __align__(16) bf16 PEs[128 * 64];
  __shared__ __align__(16) bf16 Ws[64 * 64];
  const int tid = threadIdx.x;
  const int wave = tid >> 6, lane = tid & 63;
  const int quad = lane >> 4, l16 = lane & 15;
  const int wm = (wave >> 1) * 64, wn = (wave & 1) * 32;

  const int prow = tid >> 1;          // 0..127
  const int colq = (tid & 1) * 32;
  int pp = m0 + prow; if (pp >= PP) pp = PP - 1;
  const bf16* zi = z + (size_t)pairs[pp] * 128;
  const bf16* zj = z + (size_t)pairs[PP + pp] * 128;

  floatx4 acc[4][2];
#pragma unroll
  for (int i = 0; i < 4; ++i)
#pragma unroll
    for (int j = 0; j < 2; ++j) acc[i][j] = (floatx4){0.f, 0.f, 0.f, 0.f};

#pragma unroll
  for (int kwi = 0; kwi < 2; ++kwi) {
    const int kw = kwi * 64;
    short8 va[4], vb[4];
#pragma unroll
    for (int c8 = 0; c8 < 4; ++c8) {
      va[c8] = *(const short8*)(zi + kw + colq + c8 * 8);
      vb[c8] = *(const short8*)(zj + kw + colq + c8 * 8);
    }
#pragma unroll
    for (int op = 0; op < 2; ++op) {   // 0: prod (WB), 1: absdiff (WC)
      const bf16* W = (op == 0) ? WBT : WCT;
#pragma unroll
      for (int q = 0; q < 2; ++q) {
        int c0 = q * 4096 + wave * 1024;
        int row = (c0 >> 7) + (lane >> 3);
        int ch = (lane & 7) ^ (row & 7);
        async_copy16((char*)Ws + c0, W + (size_t)(n0 + row) * 128 + kw + ch * 8);
      }
#pragma unroll
      for (int c8 = 0; c8 < 4; ++c8) {
        short8 o;
#pragma unroll
        for (int jj = 0; jj < 8; ++jj) {
          float fa = bits2f((unsigned short)va[c8][jj]);
          float fb = bits2f((unsigned short)vb[c8][jj]);
          float v = (op == 0) ? (fa * fb) : fabsf(fa - fb);
          o[jj] = f2bits(v);
        }
        int q = (tid & 1) * 4 + c8;
        *(short8*)(PEs + prow * 64 + ((q ^ (prow & 7)) << 3)) = o;
      }
      __syncthreads();
#pragma unroll
      for (int kk = 0; kk < 64; kk += 32) {
        int qb = (kk >> 3) + quad;
        short8 b0 = *frag_at(Ws, wn + l16, qb);
        short8 b1 = *frag_at(Ws, wn + 16 + l16, qb);
#pragma unroll
        for (int i = 0; i < 4; ++i) {
          short8 a = *frag_at(PEs, wm + i * 16 + l16, qb);
          acc[i][0] = __builtin_amdgcn_mfma_f32_16x16x32_bf16(a, b0, acc[i][0], 0, 0, 0);
          acc[i][1] = __builtin_amdgcn_mfma_f32_16x16x32_bf16(a, b1, acc[i][1], 0, 0, 0);
        }
      }
      __syncthreads();
    }
  }

#pragma unroll
  for (int i = 0; i < 4; ++i)
#pragma unroll
    for (int j = 0; j < 2; ++j)
#pragma unroll
      for (int r = 0; r < 4; ++r) {
        int row = m0 + wm + i * 16 + quad * 4 + r;
        int col = n0 + wn + j * 16 + l16;
        if (row < PP) P0[(size_t)row * 256 + col] = f2b(acc[i][j][r]);
      }
}

// ---------------- elementwise: D0 = gelu(ln(P0 + ZA[gi] + ZA[gj] + db0)) in place ----------------
__global__ __launch_bounds__(256) void ln_d0_k(bf16* __restrict__ D0,
                                               const int* __restrict__ pairs,
                                               const bf16* __restrict__ ZA,
                                               const float* __restrict__ db0,
                                               const float* __restrict__ g,
                                               const float* __restrict__ b) {
  int wave = threadIdx.x >> 6, lane = threadIdx.x & 63;
  int row = blockIdx.x * 4 + wave;
  if (row >= PP) return;
  int gi = pairs[row], gj = pairs[PP + row];
  bf16* p = D0 + (size_t)row * 256 + lane * 4;
  short4v xv = *(const short4v*)p;
  short4v av = *(const short4v*)(ZA + (size_t)gi * 256 + lane * 4);
  short4v bv = *(const short4v*)(ZA + (size_t)gj * 256 + lane * 4);
  float v[4];
  float s = 0.f, s2 = 0.f;
#pragma unroll
  for (int k = 0; k < 4; ++k) {
    v[k] = bits2f((unsigned short)xv[k]) + bits2f((unsigned short)av[k]) +
           bits2f((unsigned short)bv[k]) + db0[lane * 4 + k];
    s += v[k]; s2 += v[k] * v[k];
  }
  for (int off = 32; off; off >>= 1) { s += __shfl_xor(s, off); s2 += __shfl_xor(s2, off); }
  float m = s / 256.f;
  float var = s2 / 256.f - m * m;
  float rs = rsqrtf(var + 1e-5f);
  short4v ov;
#pragma unroll
  for (int k = 0; k < 4; ++k) {
    int c = lane * 4 + k;
    float y = (v[k] - m) * rs * g[c] + b[c];
    ov[k] = f2bits(gelu_f(y));
  }
  *(short4v*)p = ov;
}

// ---------------- decoder GEMM1: A = D0 (bf16) staged; P1 = A@W1^T + db1 ----------------
__global__ __launch_bounds__(256) void lngemm1_k(
    const bf16* __restrict__ D0, const bf16* __restrict__ W1t,  // [128][256]
    const float* __restrict__ bias, bf16* __restrict__ P1, int M) {
  __shared__ __align__(16) bf16 As[64 * 256];
  __shared__ __align__(16) bf16 Ws[128 * 64];
  const int tid = threadIdx.x;
  const int wave = tid >> 6, lane = tid & 63;
  const int quad = lane >> 4, l16 = lane & 15;
  const int wr = (wave >> 1) * 32;
  const int wc = (wave & 1) * 64;
  const int m0 = blockIdx.x * 64;

  // stage A (already post-LN/GELU bf16)
  {
    const int srow = tid >> 2;
    const int q4 = tid & 3;
    int grow = m0 + srow; if (grow >= M) grow = M - 1;
    const bf16* src = D0 + (size_t)grow * 256 + q4 * 64;
#pragma unroll
    for (int c8 = 0; c8 < 8; ++c8) {
      short8 o = *(const short8*)(src + c8 * 8);
      *(short8*)(As + srow * 256 + q4 * 64 + ((c8 ^ (srow & 7)) << 3)) = o;
    }
  }

  floatx4 acc[2][4];
#pragma unroll
  for (int i = 0; i < 2; ++i)
#pragma unroll
    for (int j = 0; j < 4; ++j) acc[i][j] = (floatx4){0.f, 0.f, 0.f, 0.f};

  for (int kc = 0; kc < 4; ++kc) {
#pragma unroll
    for (int q = 0; q < 4; ++q) {
      int c0 = q * 4096 + wave * 1024;
      int row = (c0 >> 7) + (lane >> 3);
      int ch = (lane & 7) ^ (row & 7);
      async_copy16((char*)Ws + c0, W1t + (size_t)row * 256 + kc * 64 + ch * 8);
    }
    __syncthreads();
#pragma unroll
    for (int kk = 0; kk < 64; kk += 32) {
      int qb = (kk >> 3) + quad;
      short8 a0 = *frag256(As, wr + l16, kc * 64, qb);
      short8 a1 = *frag256(As, wr + 16 + l16, kc * 64, qb);
#pragma unroll
      for (int j = 0; j < 4; ++j) {
        short8 bb = *frag_at(Ws, wc + j * 16 + l16, qb);
        acc[0][j] = __builtin_amdgcn_mfma_f32_16x16x32_bf16(a0, bb, acc[0][j], 0, 0, 0);
        acc[1][j] = __builtin_amdgcn_mfma_f32_16x16x32_bf16(a1, bb, acc[1][j], 0, 0, 0);
      }
    }
    __syncthreads();
  }

#pragma unroll
  for (int i = 0; i < 2; ++i)
#pragma unroll
    for (int r = 0; r < 4; ++r) {
      int row = wr + i * 16 + quad * 4 + r;
      int grow = m0 + row;
      if (grow >= M) continue;
#pragma unroll
      for (int j = 0; j < 4; ++j) {
        int col = wc + j * 16 + l16;
        P1[(size_t)grow * 128 + col] = f2b(acc[i][j][r] + bias[col]);
      }
    }
}

// ---------------- decoder GEMM2: A = gelu(ln(P1)); P2 = A@W2^T + db2 ----------------
__global__ __launch_bounds__(256) void lngemm2_k(
    const bf16* __restrict__ P1, const bf16* __restrict__ W2t,  // [64][128]
    const float* __restrict__ g, const float* __restrict__ b,
    const float* __restrict__ bias, bf16* __restrict__ P2, int M) {
  __shared__ __align__(16) bf16 As[64 * 128];
  __shared__ __align__(16) bf16 Ws[64 * 64];
  const int tid = threadIdx.x;
  const int wave = tid >> 6, lane = tid & 63;
  const int quad = lane >> 4, l16 = lane & 15;
  const int m0 = blockIdx.x * 64;

  {
    const int srow = tid >> 2;
    const int q4 = tid & 3;
    int grow = m0 + srow; if (grow >= M) grow = M - 1;
    const bf16* src = P1 + (size_t)grow * 128 + q4 * 32;
    float v[32];
    float s = 0.f, s2 = 0.f;
#pragma unroll
    for (int c8 = 0; c8 < 4; ++c8) {
      short8 x = *(const short8*)(src + c8 * 8);
#pragma unroll
      for (int jj = 0; jj < 8; ++jj) {
        float f = bits2f((unsigned short)x[jj]);
        v[c8 * 8 + jj] = f; s += f; s2 += f * f;
      }
    }
    s += __shfl_xor(s, 1); s2 += __shfl_xor(s2, 1);
    s += __shfl_xor(s, 2); s2 += __shfl_xor(s2, 2);
    float mean = s / 128.f;
    float var = s2 / 128.f - mean * mean;
    float rs = rsqrtf(var + 1e-5f);
#pragma unroll
    for (int c8 = 0; c8 < 4; ++c8) {
      short8 o;
#pragma unroll
      for (int jj = 0; jj < 8; ++jj) {
        int col = q4 * 32 + c8 * 8 + jj;
        float y = (v[c8 * 8 + jj] - mean) * rs * g[col] + b[col];
        o[jj] = f2bits(gelu_f(y));
      }
      *(short8*)(As + idx128(srow, q4 * 4 + c8)) = o;
    }
  }

  floatx4 acc[4];
#pragma unroll
  for (int j = 0; j < 4; ++j) acc[j] = (floatx4){0.f, 0.f, 0.f, 0.f};

  for (int kc = 0; kc < 2; ++kc) {
#pragma unroll
    for (int q = 0; q < 2; ++q) {
      int c0 = q * 4096 + wave * 1024;
      int row = (c0 >> 7) + (lane >> 3);
      int ch = (lane & 7) ^ (row & 7);
      async_copy16((char*)Ws + c0, W2t + (size_t)row * 128 + kc * 64 + ch * 8);
    }
    __syncthreads();
#pragma unroll
    for (int kk = 0; kk < 64; kk += 32) {
      int qb = (kk >> 3) + quad;
      short8 a = *(const short8*)(As + idx128(wave * 16 + l16, kc * 8 + qb));
#pragma unroll
      for (int j = 0; j < 4; ++j) {
        short8 bb = *frag_at(Ws, j * 16 + l16, qb);
        acc[j] = __builtin_amdgcn_mfma_f32_16x16x32_bf16(a, bb, acc[j], 0, 0, 0);
      }
    }
    __syncthreads();
  }

#pragma unroll
  for (int r = 0; r < 4; ++r) {
    int row = wave * 16 + quad * 4 + r;
    int grow = m0 + row;
    if (grow >= M) continue;
#pragma unroll
    for (int j = 0; j < 4; ++j) {
      int col = j * 16 + l16;
      P2[(size_t)grow * 64 + col] = f2b(acc[j][r] + bias[col]);
    }
  }
}

// ---------------- logits: ln + gelu + dot ----------------
__global__ __launch_bounds__(256) void logits_k(const bf16* __restrict__ P2,
                                                const float* __restrict__ g,
                                                const float* __restrict__ b,
                                                const float* __restrict__ w3,
                                                const float* __restrict__ b3,
                                                float* __restrict__ out) {
  int wave = threadIdx.x >> 6, lane = threadIdx.x & 63;
  int p = blockIdx.x * 4 + wave;
  if (p >= PP) return;
  float v = b2f(P2[(size_t)p * 64 + lane]);
  float s = v, s2 = v * v;
  for (int off = 32; off; off >>= 1) { s += __shfl_xor(s, off); s2 += __shfl_xor(s2, off); }
  float m = s / 64.f;
  float var = s2 / 64.f - m * m;
  float rs = rsqrtf(var + 1e-5f);
  float y = gelu_f((v - m) * rs * g[lane] + b[lane]);
  float t = y * w3[lane];
  for (int off = 32; off; off >>= 1) t += __shfl_xor(t, off);
  if (lane == 0) out[p] = t + b3[0];
}

// ---------------- host ----------------
extern "C" void kernel_launch(void* const* d_in, const int* in_sizes, int n_in,
                              void* d_out, int out_size, void* d_ws, size_t ws_size,
                              hipStream_t stream) {
  auto cdiv = [](int a, int b) { return (a + b - 1) / b; };

  const float* x = (const float*)d_in[0];
  const int* ei = (const int*)d_in[1];
  const int* et = (const int*)d_in[2];
  const int* gp = (const int*)d_in[3];
  const float *basis[4], *att[4], *root[4], *relatt[4], *gln[4], *bln[4];
  for (int l = 0; l < 4; ++l) {
    basis[l]  = (const float*)d_in[4 + 6 * l];
    att[l]    = (const float*)d_in[5 + 6 * l];
    root[l]   = (const float*)d_in[6 + 6 * l];
    relatt[l] = (const float*)d_in[7 + 6 * l];
    gln[l]    = (const float*)d_in[8 + 6 * l];
    bln[l]    = (const float*)d_in[9 + 6 * l];
  }
  const float* res0 = (const float*)d_in[28];
  const float* res3 = (const float*)d_in[29];
  const float* dW0 = (const float*)d_in[30]; const float* db0 = (const float*)d_in[31];
  const float* dg0 = (const float*)d_in[32]; const float* dbb0 = (const float*)d_in[33];
  const float* dW1 = (const float*)d_in[34]; const float* db1 = (const float*)d_in[35];
  const float* dg1 = (const float*)d_in[36]; const float* dbb1 = (const float*)d_in[37];
  const float* dW2 = (const float*)d_in[38]; const float* db2 = (const float*)d_in[39];
  const float* dg2 = (const float*)d_in[40]; const float* dbb2 = (const float*)d_in[41];
  const float* dW3 = (const float*)d_in[42]; const float* db3 = (const float*)d_in[43];

  char* base = (char*)d_ws;
  size_t off = 0;
  auto alloc = [&](size_t bytes) -> char* {
    char* p = base + off;
    off += (bytes + 255) & ~(size_t)255;
    return p;
  };
  bf16* X16 = (bf16*)alloc((size_t)NN * 128 * 2);
  bf16* HA  = (bf16*)alloc((size_t)NN * 256 * 2);
  bf16* HB  = (bf16*)alloc((size_t)NN * 256 * 2);
  bf16* RESB = (bf16*)alloc((size_t)NN * 256 * 2);
  bf16* ZA   = (bf16*)alloc((size_t)NN * 256 * 2);
  float* CONV = (float*)alloc((size_t)NN * 256 * 4);
  bf16* WT    = (bf16*)alloc((size_t)589824 * 2);
  bf16* RES0T = (bf16*)alloc((size_t)32768 * 2);
  bf16* RES3T = (bf16*)alloc((size_t)32768 * 2);
  bf16* WAT   = (bf16*)alloc((size_t)32768 * 2);
  bf16* WBT   = (bf16*)alloc((size_t)32768 * 2);
  bf16* WCT   = (bf16*)alloc((size_t)32768 * 2);
  bf16* DW1T  = (bf16*)alloc((size_t)32768 * 2);
  bf16* DW2T  = (bf16*)alloc((size_t)8192 * 2);
  float* ASOFT = (float*)alloc(32 * 4);
  int* COUNTS = (int*)alloc((size_t)NR * 4);
  int* SEG    = (int*)alloc((size_t)NR * 4);
  int* CUR    = (int*)alloc((size_t)NR * 4);
  int* BS     = (int*)alloc(1024 * 4);
  int* SSRC   = (int*)alloc((size_t)EE * 4);
  char* BIG = alloc(93000000);   // overlay: AGG [N,2304]bf16 (92.2MB) | P0/D0 [P,256]bf16 (51.2MB)
  bf16* AGG = (bf16*)BIG;
  bf16* D0  = (bf16*)BIG;
  bf16* P1  = (bf16*)alloc((size_t)PP * 128 * 2);
  bf16* P2  = (bf16*)alloc((size_t)PP * 64 * 2);
  (void)ws_size; (void)in_sizes; (void)n_in; (void)out_size;

  float* out_logits = (float*)d_out;
  float* out_z = (float*)d_out + PP;

  // --- CSR build ---
  hipMemsetAsync(COUNTS, 0, (size_t)NR * 4, stream);
  hipMemsetAsync(CUR, 0, (size_t)NR * 4, stream);
  hist_k<<<cdiv(EE, 256), 256, 0, stream>>>(ei + EE, et, COUNTS);
  scan1_k<<<NR / 256, 256, 0, stream>>>(COUNTS, SEG, BS);
  scan2_k<<<1, 256, 0, stream>>>(BS, NR / 256);
  scan3_k<<<NR / 256, 256, 0, stream>>>(SEG, BS);
  scatter_k<<<cdiv(EE, 256), 256, 0, stream>>>(ei, ei + EE, et, SEG, CUR, SSRC);

  // --- weight prep ---
  cvt_bf16_k<<<cdiv(NN * 128, 256), 256, 0, stream>>>(x, X16, NN * 128);
  softmax4_k<<<1, 64, 0, stream>>>(relatt[0], relatt[1], relatt[2], relatt[3], ASOFT);
  transpose_k<<<cdiv(128 * 256, 256), 256, 0, stream>>>(res0, RES0T, 128, 256);
  transpose_k<<<cdiv(256 * 128, 256), 256, 0, stream>>>(res3, RES3T, 256, 128);
  transpose_k<<<cdiv(128 * 256, 256), 256, 0, stream>>>(dW0, WAT, 128, 256);
  transpose_k<<<cdiv(128 * 256, 256), 256, 0, stream>>>(dW0 + 128 * 256, WBT, 128, 256);
  transpose_k<<<cdiv(128 * 256, 256), 256, 0, stream>>>(dW0 + 256 * 256, WCT, 128, 256);
  transpose_k<<<cdiv(256 * 128, 256), 256, 0, stream>>>(dW1, DW1T, 256, 128);
  transpose_k<<<cdiv(128 * 64, 256), 256, 0, stream>>>(dW2, DW2T, 128, 64);

  const int mb = cdiv(NN, 128);            // 157
  const int swzP4 = 8 * cdiv(mb, 8) * 4;   // nb=4
  const int swzP2 = 8 * cdiv(mb, 8) * 2;   // nb=2

  // --- layer 0: ic=128, oc=256, residual = x @ res0 ---
  prep_w_k<<<cdiv(9 * 128 * 256, 256), 256, 0, stream>>>(basis[0], att[0], root[0], ASOFT + 0, WT, 128, 7, 256, 8);
  aggregate_k<<<cdiv(NN, 16), 256, 0, stream>>>(X16, SEG, COUNTS, SSRC, AGG, 128, 4);
  gemm_plain_k<<<dim3(4, cdiv(NN, 64)), 256, 0, stream>>>(X16, RES0T, RESB, NN, 256, 128);
  gemm_f32_k<<<swzP4, 256, 0, stream>>>(AGG, WT, CONV, NN, 256, 1152, 4);
  ln_conv_k<<<cdiv(NN, 4), 256, 0, stream>>>(CONV, RESB, gln[0], bln[0], HA, nullptr, 256, 1);

  // --- layer 1 ---
  prep_w_k<<<cdiv(9 * 256 * 256, 256), 256, 0, stream>>>(basis[1], att[1], root[1], ASOFT + 8, WT, 256, 8, 256, 8);
  aggregate_k<<<cdiv(NN, 8), 256, 0, stream>>>(HA, SEG, COUNTS, SSRC, AGG, 256, 5);
  gemm_f32_k<<<swzP4, 256, 0, stream>>>(AGG, WT, CONV, NN, 256, 2304, 4);
  ln_conv_k<<<cdiv(NN, 4), 256, 0, stream>>>(CONV, HA, gln[1], bln[1], HB, nullptr, 256, 1);

  // --- layer 2 ---
  prep_w_k<<<cdiv(9 * 256 * 256, 256), 256, 0, stream>>>(basis[2], att[2], root[2], ASOFT + 16, WT, 256, 8, 256, 8);
  aggregate_k<<<cdiv(NN, 8), 256, 0, stream>>>(HB, SEG, COUNTS, SSRC, AGG, 256, 5);
  gemm_f32_k<<<swzP4, 256, 0, stream>>>(AGG, WT, CONV, NN, 256, 2304, 4);
  ln_conv_k<<<cdiv(NN, 4), 256, 0, stream>>>(CONV, HB, gln[2], bln[2], HA, nullptr, 256, 1);

  // --- layer 3: oc=128, residual = h_in @ res3, no gelu; writes z (fp32 out_z) + HB ---
  prep_w_k<<<cdiv(9 * 256 * 128, 256), 256, 0, stream>>>(basis[3], att[3], root[3], ASOFT + 24, WT, 256, 8, 128, 7);
  aggregate_k<<<cdiv(NN, 8), 256, 0, stream>>>(HA, SEG, COUNTS, SSRC, AGG, 256, 5);
  gemm_plain_k<<<dim3(2, cdiv(NN, 64)), 256, 0, stream>>>(HA, RES3T, RESB, NN, 128, 256);
  gemm_f32_k<<<swzP2, 256, 0, stream>>>(AGG, WT, CONV, NN, 128, 2304, 2);
  ln_conv_k<<<cdiv(NN, 4), 256, 0, stream>>>(CONV, RESB, gln[3], bln[3], HB, out_z, 128, 0);

  // --- decoder ---
  gemm_plain_k<<<dim3(4, cdiv(NN, 64)), 256, 0, stream>>>(HB, WAT, ZA, NN, 256, 128);
  const int pb = cdiv(PP, 128);            // 782
  const int swzPE = 8 * cdiv(pb, 8) * 4;   // nb=4
  gemm_pe_k<<<swzPE, 256, 0, stream>>>(HB, gp, WBT, WCT, D0);
  ln_d0_k<<<cdiv(PP, 4), 256, 0, stream>>>(D0, gp, ZA, db0, dg0, dbb0);
  lngemm1_k<<<cdiv(PP, 64), 256, 0, stream>>>(D0, DW1T, db1, P1, PP);
  lngemm2_k<<<cdiv(PP, 4 * 16), 256, 0, stream>>>(P1, DW2T, dg1, dbb1, db2, P2, PP);
  logits_k<<<cdiv(PP, 4), 256, 0, stream>>>(P2, dg2, dbb2, dW3, db3, out_logits);
}